// Round 2
// baseline (1187.350 us; speedup 1.0000x reference)
//
#include <hip/hip_runtime.h>
#include <hip/hip_fp16.h>
#include <math.h>

#define HID   64
#define HEADS 4
#define DH    16
#define NU    30000
#define NE_   60000
#define NV    1000
#define NTOT  91000
#define ETOT  870000
#define NSLOT 541000
#define LAYERS 2

// Edge-type tables
__device__ const int d_EOFF[14] = {0,150000,270000,330000,370000,400000,450000,
                                   570000,630000,670000,700000,750000,810000,870000};
__device__ const int d_ECNT[13] = {150000,120000,60000,40000,30000,50000,
                                   120000,60000,40000,30000,50000,60000,60000};
__device__ const int d_EST[13]  = {0,0,0,0,0,0,1,1,1,1,1,1,2};
__device__ const int d_EDT[13]  = {0,1,1,1,1,1,0,0,0,0,0,2,1};
__device__ const int d_NOFF[3]  = {0, NU, NU + NE_};
// slot base per edge type in the kvt mega-table (src-node indexed per e)
__device__ const int d_EBASE[13] = {0,30000,60000,90000,120000,150000,
                                    180000,240000,300000,360000,420000,480000,540000};
// k_kvt tiling: one wave per (edge type, 64-src-node tile)
__device__ const int d_NSRC[13] = {30000,30000,30000,30000,30000,30000,
                                   60000,60000,60000,60000,60000,60000,1000};
__device__ const int d_TOFF[13] = {0,469,938,1407,1876,2345,2814,
                                   3752,4690,5628,6566,7504,8442};
#define NWAVE_KVT 8458

struct EdgePtrs { const int* p[13]; };

typedef float f32x2 __attribute__((ext_vector_type(2)));

__device__ __forceinline__ void pk_fma(f32x2& acc, f32x2 a, f32x2 b) {
    asm("v_pk_fma_f32 %0, %1, %2, %0" : "+v"(acc) : "v"(a), "v"(b));
}

__device__ __forceinline__ int node_type(int n) {
    return (n >= NU) + (n >= NU + NE_);
}

// ---------------- input projection: h = x@W + b + emb[ids] ----------------
__global__ void k_init(const float* __restrict__ xu, const float* __restrict__ xe,
                       const float* __restrict__ xv,
                       const float* __restrict__ Wu, const float* __restrict__ bu,
                       const float* __restrict__ We, const float* __restrict__ be,
                       const float* __restrict__ Wv_, const float* __restrict__ bv,
                       const float* __restrict__ embu, const float* __restrict__ embe,
                       const float* __restrict__ embv,
                       const int* __restrict__ idu, const int* __restrict__ ide,
                       const int* __restrict__ idv,
                       float* __restrict__ h) {
    int gid = blockIdx.x * blockDim.x + threadIdx.x;
    if (gid >= NTOT * HID) return;
    int node = gid >> 6, j = gid & 63;
    const float *x, *W, *b, *emb; const int* ids; int in_dim, n;
    if (node < NU)            { n = node;           x = xu; W = Wu;  b = bu; emb = embu; ids = idu; in_dim = 32; }
    else if (node < NU + NE_) { n = node - NU;      x = xe; W = We;  b = be; emb = embe; ids = ide; in_dim = 32; }
    else                      { n = node - NU - NE_;x = xv; W = Wv_; b = bv; emb = embv; ids = idv; in_dim = 16; }
    float acc = b[j] + emb[(size_t)ids[n] * HID + j];
    for (int i = 0; i < in_dim; i++) acc += x[(size_t)n * in_dim + i] * W[i * HID + j];
    h[gid] = acc;
}

// ---------------- CSR build (exact rows, entry = slot index) ----------------
__global__ void k_cnt(EdgePtrs ep, int* __restrict__ cnt) {
    int eidx = blockIdx.x * blockDim.x + threadIdx.x;
    if (eidx >= ETOT) return;
    int e = 0;
    #pragma unroll
    for (int i = 1; i < 13; i++) e += (eidx >= d_EOFF[i]);
    int li = eidx - d_EOFF[e];
    int dst = ep.p[e][d_ECNT[e] + li];
    atomicAdd(&cnt[d_NOFF[d_EDT[e]] + dst], 1);
}

__global__ void k_scan_a(const int* __restrict__ cnt, int* __restrict__ partial) {
    __shared__ int s[256];
    int i = blockIdx.x * 256 + threadIdx.x;
    s[threadIdx.x] = (i < NTOT) ? cnt[i] : 0;
    __syncthreads();
    for (int off = 128; off > 0; off >>= 1) {
        if (threadIdx.x < off) s[threadIdx.x] += s[threadIdx.x + off];
        __syncthreads();
    }
    if (threadIdx.x == 0) partial[blockIdx.x] = s[0];
}

__global__ void k_scan_b(int* __restrict__ partial, int nblk) {
    __shared__ int s[512];
    int t = threadIdx.x;
    s[t] = (t < nblk) ? partial[t] : 0;
    __syncthreads();
    for (int off = 1; off < 512; off <<= 1) {
        int v = (t >= off) ? s[t - off] : 0;
        __syncthreads();
        s[t] += v;
        __syncthreads();
    }
    if (t < nblk) partial[t] = t ? s[t - 1] : 0;   // exclusive
}

__global__ void k_scan_c(const int* __restrict__ cnt, const int* __restrict__ partial,
                         int* __restrict__ row_ptr) {
    __shared__ int s[256];
    int i = blockIdx.x * 256 + threadIdx.x, t = threadIdx.x;
    int v = (i < NTOT) ? cnt[i] : 0;
    s[t] = v;
    __syncthreads();
    for (int off = 1; off < 256; off <<= 1) {
        int u = (t >= off) ? s[t - off] : 0;
        __syncthreads();
        s[t] += u;
        __syncthreads();
    }
    if (i < NTOT) row_ptr[i] = s[t] - v + partial[blockIdx.x];
    if (i == NTOT - 1) row_ptr[NTOT] = s[t] + partial[blockIdx.x];
}

__global__ void k_fill(EdgePtrs ep, const int* __restrict__ row_ptr,
                       int* __restrict__ cursor, int* __restrict__ csr) {
    int eidx = blockIdx.x * blockDim.x + threadIdx.x;
    if (eidx >= ETOT) return;
    int e = 0;
    #pragma unroll
    for (int i = 1; i < 13; i++) e += (eidx >= d_EOFF[i]);
    int li = eidx - d_EOFF[e];
    const int* base = ep.p[e];
    int src = base[li], dst = base[d_ECNT[e] + li];
    int dg = d_NOFF[d_EDT[e]] + dst;
    int pos = atomicAdd(&cursor[dg], 1);
    csr[row_ptr[dg] + pos] = d_EBASE[e] + src;
}

// ---------------- kqv projection (stage 1, standalone) ----------------
// R8: split from fused k_kqvt. Streaming 4-row W chunks (not a 64-reg cache)
// keeps VGPR ~48 -> clean codegen, high occupancy. h reads are block-uniform
// (scalarizable). Writes q to qagg, k|v to the kv staging buffer.
__global__ __launch_bounds__(192, 4)
void k_kqv(const float* __restrict__ h, const float* __restrict__ Wkqv,
           const float* __restrict__ bkqv,
           float* __restrict__ qagg, float* __restrict__ kv, int layer) {
    int n0 = blockIdx.x * 16;
    int t = node_type(n0);          // 16-node tiles never straddle type boundaries
    int j = threadIdx.x;
    const float* W = Wkqv + (size_t)(layer * 3 + t) * HID * 192;
    float acc[16];
    float b = bkqv[(layer * 3 + t) * 192 + j];
    #pragma unroll
    for (int n = 0; n < 16; n++) acc[n] = b;
    const float* hb = h + (size_t)n0 * 64;
    #pragma unroll
    for (int ic = 0; ic < 16; ic++) {
        float w0 = W[(4 * ic + 0) * 192 + j];
        float w1 = W[(4 * ic + 1) * 192 + j];
        float w2 = W[(4 * ic + 2) * 192 + j];
        float w3 = W[(4 * ic + 3) * 192 + j];
        #pragma unroll
        for (int n = 0; n < 16; n++) {
            float4 hv = *(const float4*)(hb + n * 64 + ic * 4);  // block-uniform
            acc[n] += hv.x * w0 + hv.y * w1 + hv.z * w2 + hv.w * w3;
        }
    }
    #pragma unroll
    for (int n = 0; n < 16; n++) {
        int node = n0 + n;
        if (node >= NTOT) break;                 // uniform; tail tile only
        if (j < 64)       kv[(size_t)node * 128 + j] = acc[n];
        else if (j < 128) qagg[(size_t)node * 64 + (j - 64)] = acc[n];
        else              kv[(size_t)node * 128 + 64 + (j - 128)] = acc[n];
    }
}

// ---------------- kvt slot table build (stage 2, standalone) ----------------
// One wave per (edge type e, tile of 64 source nodes): weights live in 32
// f32x2 regs amortized over 64 nodes; per node 8 dwordx4 loads (head groups
// share cachelines) + 16 v_pk_fma_f32 + 2 hadds + 1 packed half2 store.
__global__ __launch_bounds__(256, 4)
void k_kvt(const float* __restrict__ kv, const float* __restrict__ Wk,
           const float* __restrict__ Wv, const float* __restrict__ prel,
           __half2* __restrict__ kvt, int layer) {
    int w = blockIdx.x * 4 + (threadIdx.x >> 6);
    if (w >= NWAVE_KVT) return;
    int e = 0;
    #pragma unroll
    for (int i = 1; i < 13; i++) e += (w >= d_TOFF[i]);
    int ti = w - d_TOFF[e];
    int n0 = ti * 64;
    int nn = min(64, d_NSRC[e] - n0);
    int lane = threadIdx.x & 63, hh = lane >> 4, xo = lane & 15;

    const float* Wkp = Wk + (((size_t)layer * 13 + e) * 4 + hh) * 256 + xo;
    const float* Wvp = Wv + (((size_t)layer * 13 + e) * 4 + hh) * 256 + xo;
    float pr = prel[(layer * 13 + e) * 4 + hh] * 0.25f;
    f32x2 wk2[8], wv2[8];
    #pragma unroll
    for (int p = 0; p < 8; p++) {
        wk2[p].x = Wkp[(2 * p)     * 16] * pr;
        wk2[p].y = Wkp[(2 * p + 1) * 16] * pr;
        wv2[p].x = Wvp[(2 * p)     * 16];
        wv2[p].y = Wvp[(2 * p + 1) * 16];
    }

    const float* kvb = kv + (size_t)(d_NOFF[d_EST[e]] + n0) * 128 + hh * 16;
    __half2* outp = kvt + (size_t)(d_EBASE[e] + n0) * 64 + lane;

    auto body = [&](int n) {
        const float* kr = kvb + (size_t)n * 128;
        float4 ka = ((const float4*)kr)[0];
        float4 kb = ((const float4*)kr)[1];
        float4 kc = ((const float4*)kr)[2];
        float4 kd = ((const float4*)kr)[3];
        float4 va = ((const float4*)(kr + 64))[0];
        float4 vb = ((const float4*)(kr + 64))[1];
        float4 vc = ((const float4*)(kr + 64))[2];
        float4 vd = ((const float4*)(kr + 64))[3];
        f32x2 ak; ak.x = 0.f; ak.y = 0.f;
        f32x2 av; av.x = 0.f; av.y = 0.f;
        f32x2 p0;
        p0.x = ka.x; p0.y = ka.y; pk_fma(ak, p0, wk2[0]);
        p0.x = ka.z; p0.y = ka.w; pk_fma(ak, p0, wk2[1]);
        p0.x = kb.x; p0.y = kb.y; pk_fma(ak, p0, wk2[2]);
        p0.x = kb.z; p0.y = kb.w; pk_fma(ak, p0, wk2[3]);
        p0.x = kc.x; p0.y = kc.y; pk_fma(ak, p0, wk2[4]);
        p0.x = kc.z; p0.y = kc.w; pk_fma(ak, p0, wk2[5]);
        p0.x = kd.x; p0.y = kd.y; pk_fma(ak, p0, wk2[6]);
        p0.x = kd.z; p0.y = kd.w; pk_fma(ak, p0, wk2[7]);
        p0.x = va.x; p0.y = va.y; pk_fma(av, p0, wv2[0]);
        p0.x = va.z; p0.y = va.w; pk_fma(av, p0, wv2[1]);
        p0.x = vb.x; p0.y = vb.y; pk_fma(av, p0, wv2[2]);
        p0.x = vb.z; p0.y = vb.w; pk_fma(av, p0, wv2[3]);
        p0.x = vc.x; p0.y = vc.y; pk_fma(av, p0, wv2[4]);
        p0.x = vc.z; p0.y = vc.w; pk_fma(av, p0, wv2[5]);
        p0.x = vd.x; p0.y = vd.y; pk_fma(av, p0, wv2[6]);
        p0.x = vd.z; p0.y = vd.w; pk_fma(av, p0, wv2[7]);
        float kt = ak.x + ak.y;
        float vt = av.x + av.y;
        outp[(size_t)n * 64] = __float22half2_rn(make_float2(kt, vt));
    };
    if (nn == 64) {
        #pragma unroll 4
        for (int n = 0; n < 64; n++) body(n);
    } else {
        for (int n = 0; n < nn; n++) body(n);
    }
}

// -------- fused gather: score + online softmax + message agg --------
__device__ __forceinline__ float row_sum16(float x) {
    int v;
    v = __builtin_amdgcn_update_dpp(0, __float_as_int(x), 0xB1, 0xF, 0xF, true); // quad_perm [1,0,3,2] : xor1
    x += __int_as_float(v);
    v = __builtin_amdgcn_update_dpp(0, __float_as_int(x), 0x4E, 0xF, 0xF, true); // quad_perm [2,3,0,1] : xor2
    x += __int_as_float(v);
    v = __builtin_amdgcn_update_dpp(0, __float_as_int(x), 0x141, 0xF, 0xF, true); // row_half_mirror : xor4
    x += __int_as_float(v);
    v = __builtin_amdgcn_update_dpp(0, __float_as_int(x), 0x140, 0xF, 0xF, true); // row_mirror : xor8
    x += __int_as_float(v);
    return x;
}

__device__ __forceinline__ void osm_step(float s, float vv,
                                         float& m, float& l, float& acc) {
    float d = s - m;
    float t = __expf(-fabsf(d));    // one exp per edge
    bool pos = d > 0.f;
    m = fmaxf(m, s);
    float sc = pos ? t : 1.f;
    float es = pos ? 1.f : t;
    l   = l * sc + es;
    acc = acc * sc + es * vv;
}

__global__ __launch_bounds__(512)
void k_gather(float* __restrict__ qagg, const __half2* __restrict__ kvt,
              const int* __restrict__ row_ptr, const int* __restrict__ csr) {
    int wave = threadIdx.x >> 6, lane = threadIdx.x & 63;
    int node = blockIdx.x * 8 + wave;
    if (node >= NTOT) return;
    float q = qagg[(size_t)node * 64 + lane];   // q[h][x]
    int beg = row_ptr[node], end = row_ptr[node + 1];
    float m0 = -1e30f, l0 = 0.f, a0 = 0.f;      // even-edge chain
    float m1 = -1e30f, l1 = 0.f, a1 = 0.f;      // odd-edge chain
    for (int base = beg; base < end; base += 64) {
        int n = end - base; if (n > 64) n = 64;
        int ent = csr[base + ((lane < n) ? lane : 0)];   // 64 entries in one load
        for (int c = 0; c < n; c += 8) {
            int cn = n - c; if (cn > 8) cn = 8;
            __half2 f[8];
            #pragma unroll
            for (int k = 0; k < 8; k++) {               // batch 8 gathers (MLP)
                int idx = c + ((k < cn) ? k : 0);
                int sl = __shfl(ent, idx, 64);
                f[k] = kvt[(size_t)sl * 64 + lane];
            }
            float s8[8];
            #pragma unroll
            for (int k = 0; k < 8; k++) {               // 8 independent reductions
                if (k >= cn) break;                     // uniform branch
                s8[k] = row_sum16(q * __low2float(f[k]));
            }
            #pragma unroll
            for (int k = 0; k < 8; k += 2) {            // 2 interleaved chains
                if (k < cn)     osm_step(s8[k],   __high2float(f[k]),   m0, l0, a0);
                if (k + 1 < cn) osm_step(s8[k+1], __high2float(f[k+1]), m1, l1, a1);
            }
        }
    }
    // merge the two online-softmax states
    float M   = fmaxf(m0, m1);
    float e0  = __expf(m0 - M), e1 = __expf(m1 - M);
    float l   = l0 * e0 + l1 * e1;
    float acc = a0 * e0 + a1 * e1;
    qagg[(size_t)node * 64 + lane] = (l > 0.f) ? acc / l : 0.f;
}

// ------- epilogue: gelu -> @Wout + bout -> skip-gate -> relu [-> l2norm on last]
__global__ __launch_bounds__(256)
void k_out(const float* __restrict__ agg, const float* __restrict__ Wout,
           const float* __restrict__ bout, const float* __restrict__ skip,
           float* __restrict__ h, float* __restrict__ out, int layer, int last) {
    int b = blockIdx.x; int t, n0, lim;
    if (b < 938)       { t = 0; n0 = b * 32;                 lim = NU; }
    else if (b < 2813) { t = 1; n0 = NU + (b - 938) * 32;    lim = NU + NE_; }
    else               { t = 2; n0 = NU + NE_ + (b - 2813) * 32; lim = NTOT; }
    int nn = min(32, lim - n0);
    __shared__ float gs[32][64];
    for (int i = threadIdx.x; i < nn * 64; i += 256) {
        float o = agg[(size_t)n0 * 64 + i];
        gs[i >> 6][i & 63] = 0.5f * o * (1.f + erff(o * 0.70710678118654752f));
    }
    __syncthreads();
    int j = threadIdx.x & 63, g = threadIdx.x >> 6;   // 4 waves x 8 nodes
    const float* W = Wout + (size_t)(layer * 3 + t) * HID * HID;
    float bb = bout[(layer * 3 + t) * HID + j];
    float acc[8];
    #pragma unroll
    for (int n = 0; n < 8; n++) acc[n] = bb;
    for (int i = 0; i < 64; i++) {
        float w = W[i * 64 + j];
        #pragma unroll
        for (int n = 0; n < 8; n++) acc[n] += gs[g * 8 + n][i] * w;
    }
    float gk = 1.f / (1.f + __expf(-skip[layer * 3 + t]));
    #pragma unroll
    for (int n = 0; n < 8; n++) {
        int node = n0 + g * 8 + n;
        if (node >= lim) continue;
        float r = gk * acc[n] + (1.f - gk) * h[(size_t)node * 64 + j];
        r = fmaxf(r, 0.f);                              // relu
        if (!last) {
            h[(size_t)node * 64 + j] = r;
        } else {                                        // fused l2 normalize
            float ss = r * r;
            ss += __shfl_xor(ss, 1, 64);  ss += __shfl_xor(ss, 2, 64);
            ss += __shfl_xor(ss, 4, 64);  ss += __shfl_xor(ss, 8, 64);
            ss += __shfl_xor(ss, 16, 64); ss += __shfl_xor(ss, 32, 64);
            float nrm = fmaxf(sqrtf(ss), 1e-12f);
            out[(size_t)node * 64 + j] = r / nrm;
        }
    }
}

extern "C" void kernel_launch(void* const* d_in, const int* in_sizes, int n_in,
                              void* d_out, int out_size, void* d_ws, size_t ws_size,
                              hipStream_t stream) {
    const float* xu   = (const float*)d_in[0];
    const float* xe   = (const float*)d_in[1];
    const float* xv   = (const float*)d_in[2];
    const float* Wu   = (const float*)d_in[3];
    const float* bu   = (const float*)d_in[4];
    const float* We   = (const float*)d_in[5];
    const float* be   = (const float*)d_in[6];
    const float* Wv_  = (const float*)d_in[7];
    const float* bv   = (const float*)d_in[8];
    const float* embu = (const float*)d_in[9];
    const float* embe = (const float*)d_in[10];
    const float* embv = (const float*)d_in[11];
    const float* Wkqv = (const float*)d_in[12];
    const float* bkqv = (const float*)d_in[13];
    const float* Wk   = (const float*)d_in[14];
    const float* Wv   = (const float*)d_in[15];
    const float* prel = (const float*)d_in[16];
    const float* Wout = (const float*)d_in[17];
    const float* bout = (const float*)d_in[18];
    const float* skip = (const float*)d_in[19];
    const int*   idu  = (const int*)d_in[20];
    const int*   ide  = (const int*)d_in[21];
    const int*   idv  = (const int*)d_in[22];
    EdgePtrs ep;
    for (int e = 0; e < 13; e++) ep.p[e] = (const int*)d_in[23 + e];

    float* ws  = (float*)d_ws;
    float* h      = ws;                                    // NTOT*64 f32
    float* qagg   = h    + (size_t)NTOT * HID;             // NTOT*64 f32 (q, then agg)
    float* kv     = qagg + (size_t)NTOT * HID;             // NTOT*128 f32 (k|v staging)
    __half2* kvt  = (__half2*)(kv + (size_t)NTOT * 128);   // NSLOT*64 half2
    int* cnt     = (int*)(kvt + (size_t)NSLOT * HID);      // NTOT
    int* cursor  = cnt + NTOT;                             // NTOT
    int* row_ptr = cursor + NTOT;                          // NTOT+1
    int* partial = row_ptr + NTOT + 1;                     // 512
    int* csr     = partial + 512;                          // ETOT int

    k_init<<<(NTOT * HID + 255) / 256, 256, 0, stream>>>(
        xu, xe, xv, Wu, bu, We, be, Wv_, bv, embu, embe, embv, idu, ide, idv, h);

    // CSR build (edges are layer-invariant); exact rows, entry = slot id
    hipMemsetAsync(cnt, 0, (size_t)2 * NTOT * 4, stream);   // cnt + cursor
    int nblk = (NTOT + 255) / 256;   // 356
    k_cnt<<<(ETOT + 255) / 256, 256, 0, stream>>>(ep, cnt);
    k_scan_a<<<nblk, 256, 0, stream>>>(cnt, partial);
    k_scan_b<<<1, 512, 0, stream>>>(partial, nblk);
    k_scan_c<<<nblk, 256, 0, stream>>>(cnt, partial, row_ptr);
    k_fill<<<(ETOT + 255) / 256, 256, 0, stream>>>(ep, row_ptr, cursor, csr);

    for (int l = 0; l < LAYERS; l++) {
        k_kqv<<<(NTOT + 15) / 16, 192, 0, stream>>>(h, Wkqv, bkqv, qagg, kv, l);
        k_kvt<<<(NWAVE_KVT + 3) / 4, 256, 0, stream>>>(kv, Wk, Wv, prel, kvt, l);
        k_gather<<<(NTOT + 7) / 8, 512, 0, stream>>>(qagg, kvt, row_ptr, csr);
        k_out<<<2845, 256, 0, stream>>>(qagg, Wout, bout, skip, h,
                                        (float*)d_out, l, l == LAYERS - 1);
    }
}

// Round 3
// 686.347 us; speedup vs baseline: 1.7300x; 1.7300x over previous
//
#include <hip/hip_runtime.h>
#include <hip/hip_fp16.h>
#include <math.h>

#define HID   64
#define HEADS 4
#define DH    16
#define NU    30000
#define NE_   60000
#define NV    1000
#define NTOT  91000
#define ETOT  870000
#define NSLOT 541000
#define LAYERS 2

// Edge-type tables
__device__ const int d_EOFF[14] = {0,150000,270000,330000,370000,400000,450000,
                                   570000,630000,670000,700000,750000,810000,870000};
__device__ const int d_ECNT[13] = {150000,120000,60000,40000,30000,50000,
                                   120000,60000,40000,30000,50000,60000,60000};
__device__ const int d_EST[13]  = {0,0,0,0,0,0,1,1,1,1,1,1,2};
__device__ const int d_EDT[13]  = {0,1,1,1,1,1,0,0,0,0,0,2,1};
__device__ const int d_NOFF[3]  = {0, NU, NU + NE_};
// slot base per edge type in the kvt mega-table (src-node indexed per e)
__device__ const int d_EBASE[13] = {0,30000,60000,90000,120000,150000,
                                    180000,240000,300000,360000,420000,480000,540000};

struct EdgePtrs { const int* p[13]; };

typedef float f32x2 __attribute__((ext_vector_type(2)));

__device__ __forceinline__ void pk_fma(f32x2& acc, f32x2 a, f32x2 b) {
    asm("v_pk_fma_f32 %0, %1, %2, %0" : "+v"(acc) : "v"(a), "v"(b));
}

__device__ __forceinline__ int node_type(int n) {
    return (n >= NU) + (n >= NU + NE_);
}

// ---------------- input projection: h = x@W + b + emb[ids] ----------------
__global__ void k_init(const float* __restrict__ xu, const float* __restrict__ xe,
                       const float* __restrict__ xv,
                       const float* __restrict__ Wu, const float* __restrict__ bu,
                       const float* __restrict__ We, const float* __restrict__ be,
                       const float* __restrict__ Wv_, const float* __restrict__ bv,
                       const float* __restrict__ embu, const float* __restrict__ embe,
                       const float* __restrict__ embv,
                       const int* __restrict__ idu, const int* __restrict__ ide,
                       const int* __restrict__ idv,
                       float* __restrict__ h) {
    int gid = blockIdx.x * blockDim.x + threadIdx.x;
    if (gid >= NTOT * HID) return;
    int node = gid >> 6, j = gid & 63;
    const float *x, *W, *b, *emb; const int* ids; int in_dim, n;
    if (node < NU)            { n = node;           x = xu; W = Wu;  b = bu; emb = embu; ids = idu; in_dim = 32; }
    else if (node < NU + NE_) { n = node - NU;      x = xe; W = We;  b = be; emb = embe; ids = ide; in_dim = 32; }
    else                      { n = node - NU - NE_;x = xv; W = Wv_; b = bv; emb = embv; ids = idv; in_dim = 16; }
    float acc = b[j] + emb[(size_t)ids[n] * HID + j];
    for (int i = 0; i < in_dim; i++) acc += x[(size_t)n * in_dim + i] * W[i * HID + j];
    h[gid] = acc;
}

// ---------------- CSR build (exact rows, entry = slot index) ----------------
__global__ void k_cnt(EdgePtrs ep, int* __restrict__ cnt) {
    int eidx = blockIdx.x * blockDim.x + threadIdx.x;
    if (eidx >= ETOT) return;
    int e = 0;
    #pragma unroll
    for (int i = 1; i < 13; i++) e += (eidx >= d_EOFF[i]);
    int li = eidx - d_EOFF[e];
    int dst = ep.p[e][d_ECNT[e] + li];
    atomicAdd(&cnt[d_NOFF[d_EDT[e]] + dst], 1);
}

__global__ void k_scan_a(const int* __restrict__ cnt, int* __restrict__ partial) {
    __shared__ int s[256];
    int i = blockIdx.x * 256 + threadIdx.x;
    s[threadIdx.x] = (i < NTOT) ? cnt[i] : 0;
    __syncthreads();
    for (int off = 128; off > 0; off >>= 1) {
        if (threadIdx.x < off) s[threadIdx.x] += s[threadIdx.x + off];
        __syncthreads();
    }
    if (threadIdx.x == 0) partial[blockIdx.x] = s[0];
}

__global__ void k_scan_b(int* __restrict__ partial, int nblk) {
    __shared__ int s[512];
    int t = threadIdx.x;
    s[t] = (t < nblk) ? partial[t] : 0;
    __syncthreads();
    for (int off = 1; off < 512; off <<= 1) {
        int v = (t >= off) ? s[t - off] : 0;
        __syncthreads();
        s[t] += v;
        __syncthreads();
    }
    if (t < nblk) partial[t] = t ? s[t - 1] : 0;   // exclusive
}

__global__ void k_scan_c(const int* __restrict__ cnt, const int* __restrict__ partial,
                         int* __restrict__ row_ptr) {
    __shared__ int s[256];
    int i = blockIdx.x * 256 + threadIdx.x, t = threadIdx.x;
    int v = (i < NTOT) ? cnt[i] : 0;
    s[t] = v;
    __syncthreads();
    for (int off = 1; off < 256; off <<= 1) {
        int u = (t >= off) ? s[t - off] : 0;
        __syncthreads();
        s[t] += u;
        __syncthreads();
    }
    if (i < NTOT) row_ptr[i] = s[t] - v + partial[blockIdx.x];
    if (i == NTOT - 1) row_ptr[NTOT] = s[t] + partial[blockIdx.x];
}

__global__ void k_fill(EdgePtrs ep, const int* __restrict__ row_ptr,
                       int* __restrict__ cursor, int* __restrict__ csr) {
    int eidx = blockIdx.x * blockDim.x + threadIdx.x;
    if (eidx >= ETOT) return;
    int e = 0;
    #pragma unroll
    for (int i = 1; i < 13; i++) e += (eidx >= d_EOFF[i]);
    int li = eidx - d_EOFF[e];
    const int* base = ep.p[e];
    int src = base[li], dst = base[d_ECNT[e] + li];
    int dg = d_NOFF[d_EDT[e]] + dst;
    int pos = atomicAdd(&cursor[dg], 1);
    csr[row_ptr[dg] + pos] = d_EBASE[e] + src;
}

// ---------------- fused kqv projection + kvt slot table build ----------------
// R9: stage 1 reads h from a TRANSPOSED LDS tile (hT[i][n], i-major) so all
//     64 lanes broadcast-read the same address (imm-offset ds_read_b128, no
//     per-read address VALU), and accumulates node-PAIRS with v_pk_fma_f32
//     (512 pk-FMA instead of 1024 scalar FMA + 256 addressed global loads).
//     Stage 2 uses the same packed-pair dot (16 pk_fma + 2 hadds per k,v pair)
//     verified numerically in R8's k_kvt. Same math, reassociated only.
__global__ __launch_bounds__(192, 3)
void k_kqvt(const float* __restrict__ h, const float* __restrict__ Wkqv,
            const float* __restrict__ bkqv, const float* __restrict__ Wk,
            const float* __restrict__ Wv, const float* __restrict__ prel,
            float* __restrict__ qagg, __half2* __restrict__ kvt, int layer) {
    int n0 = blockIdx.x * 16;
    int t = node_type(n0);          // 16-node tiles never straddle type boundaries
    __shared__ float hT[64][16];    // transposed h tile: hT[i][n]
    __shared__ float kq[16][192];   // per node: k 0..63 | q 64..127 | v 128..191
    int j = threadIdx.x;

    // ---- phase A: cooperative coalesced load of h tile, transposed into LDS
    const float* hb = h + (size_t)n0 * 64;
    for (int i = j; i < 256; i += 192) {
        int n = i >> 4, ic = i & 15;          // node, 4-float chunk of k-dim
        float4 hv = *(const float4*)(hb + n * 64 + ic * 4);   // coalesced
        hT[ic * 4 + 0][n] = hv.x;
        hT[ic * 4 + 1][n] = hv.y;
        hT[ic * 4 + 2][n] = hv.z;
        hT[ic * 4 + 3][n] = hv.w;
    }
    __syncthreads();

    // ---- stage 1: column j of kqv for 16 nodes, node-pair packed FMA
    const float* Wc = Wkqv + (size_t)(layer * 3 + t) * HID * 192 + j;
    float b = bkqv[(layer * 3 + t) * 192 + j];
    f32x2 acc2[8];
    #pragma unroll
    for (int p = 0; p < 8; p++) { acc2[p].x = b; acc2[p].y = b; }
    #pragma unroll
    for (int i = 0; i < 64; i++) {
        float w = Wc[(size_t)i * 192];
        f32x2 wp; wp.x = w; wp.y = w;
        #pragma unroll
        for (int qd = 0; qd < 4; qd++) {      // 4 broadcast b128 reads -> 16 nodes
            float4 hv = *(const float4*)(&hT[i][qd * 4]);
            f32x2 p0; p0.x = hv.x; p0.y = hv.y;
            pk_fma(acc2[2 * qd], p0, wp);
            f32x2 p1; p1.x = hv.z; p1.y = hv.w;
            pk_fma(acc2[2 * qd + 1], p1, wp);
        }
    }
    #pragma unroll
    for (int p = 0; p < 8; p++) {
        kq[2 * p][j]     = acc2[p].x;
        kq[2 * p + 1][j] = acc2[p].y;
    }
    if (j >= 64 && j < 128) {
        #pragma unroll
        for (int p = 0; p < 8; p++) {
            if (n0 + 2 * p < NTOT)     qagg[(size_t)(n0 + 2 * p) * 64 + (j - 64)]     = acc2[p].x;
            if (n0 + 2 * p + 1 < NTOT) qagg[(size_t)(n0 + 2 * p + 1) * 64 + (j - 64)] = acc2[p].y;
        }
    }
    __syncthreads();

    // ---- stage 2: emit kvt slots for the edge types sourced by this node type
    int wave = j >> 6, lane = j & 63;
    int hh = lane >> 4, xo = lane & 15;
    int ne = (t == 2) ? 1 : 6;
    int e0 = (t == 0) ? 0 : (t == 1) ? 6 : 12;
    int eA = e0 + wave, eB = e0 + wave + 3;
    bool vA = wave < ne, vB = wave + 3 < ne;
    int nt = n0 - d_NOFF[t];
    f32x2 wkA[8], wvA[8], wkB[8], wvB[8];
    int sbA = 0, sbB = 0;
    if (vA) {
        const float* Wkp = Wk + (((size_t)layer * 13 + eA) * 4 + hh) * 256 + xo;
        const float* Wvp = Wv + (((size_t)layer * 13 + eA) * 4 + hh) * 256 + xo;
        float pr = prel[(layer * 13 + eA) * 4 + hh] * 0.25f;
        #pragma unroll
        for (int p = 0; p < 8; p++) {
            wkA[p].x = Wkp[(2 * p)     * 16] * pr;
            wkA[p].y = Wkp[(2 * p + 1) * 16] * pr;
            wvA[p].x = Wvp[(2 * p)     * 16];
            wvA[p].y = Wvp[(2 * p + 1) * 16];
        }
        sbA = d_EBASE[eA] + nt;
    }
    if (vB) {
        const float* Wkp = Wk + (((size_t)layer * 13 + eB) * 4 + hh) * 256 + xo;
        const float* Wvp = Wv + (((size_t)layer * 13 + eB) * 4 + hh) * 256 + xo;
        float pr = prel[(layer * 13 + eB) * 4 + hh] * 0.25f;
        #pragma unroll
        for (int p = 0; p < 8; p++) {
            wkB[p].x = Wkp[(2 * p)     * 16] * pr;
            wkB[p].y = Wkp[(2 * p + 1) * 16] * pr;
            wvB[p].x = Wvp[(2 * p)     * 16];
            wvB[p].y = Wvp[(2 * p + 1) * 16];
        }
        sbB = d_EBASE[eB] + nt;
    }
    #pragma unroll
    for (int n = 0; n < 16; n++) {
        bool ok = (n0 + n) < NTOT;                 // uniform; false only in tail tile
        const float* kr = &kq[n][hh * 16];
        const float* vr = &kq[n][128 + hh * 16];
        float4 k0 = ((const float4*)kr)[0];
        float4 k1 = ((const float4*)kr)[1];
        float4 k2 = ((const float4*)kr)[2];
        float4 k3 = ((const float4*)kr)[3];
        float4 v0 = ((const float4*)vr)[0];
        float4 v1 = ((const float4*)vr)[1];
        float4 v2 = ((const float4*)vr)[2];
        float4 v3 = ((const float4*)vr)[3];
        if (vA & ok) {
            f32x2 ak; ak.x = 0.f; ak.y = 0.f;
            f32x2 av; av.x = 0.f; av.y = 0.f;
            f32x2 p0;
            p0.x = k0.x; p0.y = k0.y; pk_fma(ak, p0, wkA[0]);
            p0.x = k0.z; p0.y = k0.w; pk_fma(ak, p0, wkA[1]);
            p0.x = k1.x; p0.y = k1.y; pk_fma(ak, p0, wkA[2]);
            p0.x = k1.z; p0.y = k1.w; pk_fma(ak, p0, wkA[3]);
            p0.x = k2.x; p0.y = k2.y; pk_fma(ak, p0, wkA[4]);
            p0.x = k2.z; p0.y = k2.w; pk_fma(ak, p0, wkA[5]);
            p0.x = k3.x; p0.y = k3.y; pk_fma(ak, p0, wkA[6]);
            p0.x = k3.z; p0.y = k3.w; pk_fma(ak, p0, wkA[7]);
            p0.x = v0.x; p0.y = v0.y; pk_fma(av, p0, wvA[0]);
            p0.x = v0.z; p0.y = v0.w; pk_fma(av, p0, wvA[1]);
            p0.x = v1.x; p0.y = v1.y; pk_fma(av, p0, wvA[2]);
            p0.x = v1.z; p0.y = v1.w; pk_fma(av, p0, wvA[3]);
            p0.x = v2.x; p0.y = v2.y; pk_fma(av, p0, wvA[4]);
            p0.x = v2.z; p0.y = v2.w; pk_fma(av, p0, wvA[5]);
            p0.x = v3.x; p0.y = v3.y; pk_fma(av, p0, wvA[6]);
            p0.x = v3.z; p0.y = v3.w; pk_fma(av, p0, wvA[7]);
            float kt = ak.x + ak.y;
            float vt = av.x + av.y;
            kvt[(size_t)(sbA + n) * 64 + lane] = __float22half2_rn(make_float2(kt, vt));
        }
        if (vB & ok) {
            f32x2 ak; ak.x = 0.f; ak.y = 0.f;
            f32x2 av; av.x = 0.f; av.y = 0.f;
            f32x2 p0;
            p0.x = k0.x; p0.y = k0.y; pk_fma(ak, p0, wkB[0]);
            p0.x = k0.z; p0.y = k0.w; pk_fma(ak, p0, wkB[1]);
            p0.x = k1.x; p0.y = k1.y; pk_fma(ak, p0, wkB[2]);
            p0.x = k1.z; p0.y = k1.w; pk_fma(ak, p0, wkB[3]);
            p0.x = k2.x; p0.y = k2.y; pk_fma(ak, p0, wkB[4]);
            p0.x = k2.z; p0.y = k2.w; pk_fma(ak, p0, wkB[5]);
            p0.x = k3.x; p0.y = k3.y; pk_fma(ak, p0, wkB[6]);
            p0.x = k3.z; p0.y = k3.w; pk_fma(ak, p0, wkB[7]);
            p0.x = v0.x; p0.y = v0.y; pk_fma(av, p0, wvB[0]);
            p0.x = v0.z; p0.y = v0.w; pk_fma(av, p0, wvB[1]);
            p0.x = v1.x; p0.y = v1.y; pk_fma(av, p0, wvB[2]);
            p0.x = v1.z; p0.y = v1.w; pk_fma(av, p0, wvB[3]);
            p0.x = v2.x; p0.y = v2.y; pk_fma(av, p0, wvB[4]);
            p0.x = v2.z; p0.y = v2.w; pk_fma(av, p0, wvB[5]);
            p0.x = v3.x; p0.y = v3.y; pk_fma(av, p0, wvB[6]);
            p0.x = v3.z; p0.y = v3.w; pk_fma(av, p0, wvB[7]);
            float kt = ak.x + ak.y;
            float vt = av.x + av.y;
            kvt[(size_t)(sbB + n) * 64 + lane] = __float22half2_rn(make_float2(kt, vt));
        }
    }
}

// -------- fused gather: score + online softmax + message agg --------
__device__ __forceinline__ float row_sum16(float x) {
    int v;
    v = __builtin_amdgcn_update_dpp(0, __float_as_int(x), 0xB1, 0xF, 0xF, true); // quad_perm [1,0,3,2] : xor1
    x += __int_as_float(v);
    v = __builtin_amdgcn_update_dpp(0, __float_as_int(x), 0x4E, 0xF, 0xF, true); // quad_perm [2,3,0,1] : xor2
    x += __int_as_float(v);
    v = __builtin_amdgcn_update_dpp(0, __float_as_int(x), 0x141, 0xF, 0xF, true); // row_half_mirror : xor4
    x += __int_as_float(v);
    v = __builtin_amdgcn_update_dpp(0, __float_as_int(x), 0x140, 0xF, 0xF, true); // row_mirror : xor8
    x += __int_as_float(v);
    return x;
}

__device__ __forceinline__ void osm_step(float s, float vv,
                                         float& m, float& l, float& acc) {
    float d = s - m;
    float t = __expf(-fabsf(d));    // one exp per edge
    bool pos = d > 0.f;
    m = fmaxf(m, s);
    float sc = pos ? t : 1.f;
    float es = pos ? 1.f : t;
    l   = l * sc + es;
    acc = acc * sc + es * vv;
}

__global__ __launch_bounds__(512)
void k_gather(float* __restrict__ qagg, const __half2* __restrict__ kvt,
              const int* __restrict__ row_ptr, const int* __restrict__ csr) {
    int wave = threadIdx.x >> 6, lane = threadIdx.x & 63;
    int node = blockIdx.x * 8 + wave;
    if (node >= NTOT) return;
    float q = qagg[(size_t)node * 64 + lane];   // q[h][x]
    int beg = row_ptr[node], end = row_ptr[node + 1];
    float m0 = -1e30f, l0 = 0.f, a0 = 0.f;      // even-edge chain
    float m1 = -1e30f, l1 = 0.f, a1 = 0.f;      // odd-edge chain
    for (int base = beg; base < end; base += 64) {
        int n = end - base; if (n > 64) n = 64;
        int ent = csr[base + ((lane < n) ? lane : 0)];   // 64 entries in one load
        for (int c = 0; c < n; c += 8) {
            int cn = n - c; if (cn > 8) cn = 8;
            __half2 f[8];
            #pragma unroll
            for (int k = 0; k < 8; k++) {               // batch 8 gathers (MLP)
                int idx = c + ((k < cn) ? k : 0);
                int sl = __shfl(ent, idx, 64);
                f[k] = kvt[(size_t)sl * 64 + lane];
            }
            float s8[8];
            #pragma unroll
            for (int k = 0; k < 8; k++) {               // 8 independent reductions
                if (k >= cn) break;                     // uniform branch
                s8[k] = row_sum16(q * __low2float(f[k]));
            }
            #pragma unroll
            for (int k = 0; k < 8; k += 2) {            // 2 interleaved chains
                if (k < cn)     osm_step(s8[k],   __high2float(f[k]),   m0, l0, a0);
                if (k + 1 < cn) osm_step(s8[k+1], __high2float(f[k+1]), m1, l1, a1);
            }
        }
    }
    // merge the two online-softmax states
    float M   = fmaxf(m0, m1);
    float e0  = __expf(m0 - M), e1 = __expf(m1 - M);
    float l   = l0 * e0 + l1 * e1;
    float acc = a0 * e0 + a1 * e1;
    qagg[(size_t)node * 64 + lane] = (l > 0.f) ? acc / l : 0.f;
}

// ------- epilogue: gelu -> @Wout + bout -> skip-gate -> relu [-> l2norm on last]
__global__ __launch_bounds__(256)
void k_out(const float* __restrict__ agg, const float* __restrict__ Wout,
           const float* __restrict__ bout, const float* __restrict__ skip,
           float* __restrict__ h, float* __restrict__ out, int layer, int last) {
    int b = blockIdx.x; int t, n0, lim;
    if (b < 938)       { t = 0; n0 = b * 32;                 lim = NU; }
    else if (b < 2813) { t = 1; n0 = NU + (b - 938) * 32;    lim = NU + NE_; }
    else               { t = 2; n0 = NU + NE_ + (b - 2813) * 32; lim = NTOT; }
    int nn = min(32, lim - n0);
    __shared__ float gs[32][64];
    for (int i = threadIdx.x; i < nn * 64; i += 256) {
        float o = agg[(size_t)n0 * 64 + i];
        gs[i >> 6][i & 63] = 0.5f * o * (1.f + erff(o * 0.70710678118654752f));
    }
    __syncthreads();
    int j = threadIdx.x & 63, g = threadIdx.x >> 6;   // 4 waves x 8 nodes
    const float* W = Wout + (size_t)(layer * 3 + t) * HID * HID;
    float bb = bout[(layer * 3 + t) * HID + j];
    float acc[8];
    #pragma unroll
    for (int n = 0; n < 8; n++) acc[n] = bb;
    for (int i = 0; i < 64; i++) {
        float w = W[i * 64 + j];
        #pragma unroll
        for (int n = 0; n < 8; n++) acc[n] += gs[g * 8 + n][i] * w;
    }
    float gk = 1.f / (1.f + __expf(-skip[layer * 3 + t]));
    #pragma unroll
    for (int n = 0; n < 8; n++) {
        int node = n0 + g * 8 + n;
        if (node >= lim) continue;
        float r = gk * acc[n] + (1.f - gk) * h[(size_t)node * 64 + j];
        r = fmaxf(r, 0.f);                              // relu
        if (!last) {
            h[(size_t)node * 64 + j] = r;
        } else {                                        // fused l2 normalize
            float ss = r * r;
            ss += __shfl_xor(ss, 1, 64);  ss += __shfl_xor(ss, 2, 64);
            ss += __shfl_xor(ss, 4, 64);  ss += __shfl_xor(ss, 8, 64);
            ss += __shfl_xor(ss, 16, 64); ss += __shfl_xor(ss, 32, 64);
            float nrm = fmaxf(sqrtf(ss), 1e-12f);
            out[(size_t)node * 64 + j] = r / nrm;
        }
    }
}

extern "C" void kernel_launch(void* const* d_in, const int* in_sizes, int n_in,
                              void* d_out, int out_size, void* d_ws, size_t ws_size,
                              hipStream_t stream) {
    const float* xu   = (const float*)d_in[0];
    const float* xe   = (const float*)d_in[1];
    const float* xv   = (const float*)d_in[2];
    const float* Wu   = (const float*)d_in[3];
    const float* bu   = (const float*)d_in[4];
    const float* We   = (const float*)d_in[5];
    const float* be   = (const float*)d_in[6];
    const float* Wv_  = (const float*)d_in[7];
    const float* bv   = (const float*)d_in[8];
    const float* embu = (const float*)d_in[9];
    const float* embe = (const float*)d_in[10];
    const float* embv = (const float*)d_in[11];
    const float* Wkqv = (const float*)d_in[12];
    const float* bkqv = (const float*)d_in[13];
    const float* Wk   = (const float*)d_in[14];
    const float* Wv   = (const float*)d_in[15];
    const float* prel = (const float*)d_in[16];
    const float* Wout = (const float*)d_in[17];
    const float* bout = (const float*)d_in[18];
    const float* skip = (const float*)d_in[19];
    const int*   idu  = (const int*)d_in[20];
    const int*   ide  = (const int*)d_in[21];
    const int*   idv  = (const int*)d_in[22];
    EdgePtrs ep;
    for (int e = 0; e < 13; e++) ep.p[e] = (const int*)d_in[23 + e];

    float* ws  = (float*)d_ws;
    float* h      = ws;                                    // NTOT*64 f32
    float* qagg   = h    + (size_t)NTOT * HID;             // NTOT*64 f32 (q, then agg)
    __half2* kvt  = (__half2*)(qagg + (size_t)NTOT * HID); // NSLOT*64 half2
    int* cnt     = (int*)(kvt + (size_t)NSLOT * HID);      // NTOT
    int* cursor  = cnt + NTOT;                             // NTOT
    int* row_ptr = cursor + NTOT;                          // NTOT+1
    int* partial = row_ptr + NTOT + 1;                     // 512
    int* csr     = partial + 512;                          // ETOT int

    k_init<<<(NTOT * HID + 255) / 256, 256, 0, stream>>>(
        xu, xe, xv, Wu, bu, We, be, Wv_, bv, embu, embe, embv, idu, ide, idv, h);

    // CSR build (edges are layer-invariant); exact rows, entry = slot id
    hipMemsetAsync(cnt, 0, (size_t)2 * NTOT * 4, stream);   // cnt + cursor
    int nblk = (NTOT + 255) / 256;   // 356
    k_cnt<<<(ETOT + 255) / 256, 256, 0, stream>>>(ep, cnt);
    k_scan_a<<<nblk, 256, 0, stream>>>(cnt, partial);
    k_scan_b<<<1, 512, 0, stream>>>(partial, nblk);
    k_scan_c<<<nblk, 256, 0, stream>>>(cnt, partial, row_ptr);
    k_fill<<<(ETOT + 255) / 256, 256, 0, stream>>>(ep, row_ptr, cursor, csr);

    for (int l = 0; l < LAYERS; l++) {
        k_kqvt<<<(NTOT + 15) / 16, 192, 0, stream>>>(h, Wkqv, bkqv, Wk, Wv, prel,
                                                     qagg, kvt, l);
        k_gather<<<(NTOT + 7) / 8, 512, 0, stream>>>(qagg, kvt, row_ptr, csr);
        k_out<<<2845, 256, 0, stream>>>(qagg, Wout, bout, skip, h,
                                        (float*)d_out, l, l == LAYERS - 1);
    }
}